// Round 1
// 107.302 us; speedup vs baseline: 1.1178x; 1.1178x over previous
//
#include <hip/hip_runtime.h>
#include <hip/hip_bf16.h>

#define BATCH 65536
#define IN    64
#define H     128
#define NA    16
#define NBLK  256      // 1 block per CU, 155 KB LDS
#define TPB   1024     // 16 waves; each wave owns 16 batch rows

typedef __bf16 bf16x8 __attribute__((ext_vector_type(8)));
typedef float  f32x4  __attribute__((ext_vector_type(4)));

union Frag { uint4 u; bf16x8 v; };
struct F32x8 { float4 a, b; };

#define EXP2F(v) __builtin_amdgcn_exp2f(v)
#define RCPF(v)  __builtin_amdgcn_rcpf(v)
#define K1 1.442695041f   // log2(e)
#define K2 2.885390082f   // 2*log2(e)

__device__ __forceinline__ F32x8 ld8f(const float* p) {
    F32x8 r;
    r.a = *reinterpret_cast<const float4*>(p);
    r.b = *reinterpret_cast<const float4*>(p + 4);
    return r;
}
__device__ __forceinline__ Frag cvt8(F32x8 x) {
    Frag f;
    f.v[0]=(__bf16)x.a.x; f.v[1]=(__bf16)x.a.y; f.v[2]=(__bf16)x.a.z; f.v[3]=(__bf16)x.a.w;
    f.v[4]=(__bf16)x.b.x; f.v[5]=(__bf16)x.b.y; f.v[6]=(__bf16)x.b.z; f.v[7]=(__bf16)x.b.w;
    return f;
}
__device__ __forceinline__ Frag cvt44(float4 a, float4 b) {
    Frag f;
    f.v[0]=(__bf16)a.x; f.v[1]=(__bf16)a.y; f.v[2]=(__bf16)a.z; f.v[3]=(__bf16)a.w;
    f.v[4]=(__bf16)b.x; f.v[5]=(__bf16)b.y; f.v[6]=(__bf16)b.z; f.v[7]=(__bf16)b.w;
    return f;
}
__device__ __forceinline__ unsigned pk2(float lo, float hi) {
    unsigned short l = __builtin_bit_cast(unsigned short, (__bf16)lo);
    unsigned short h = __builtin_bit_cast(unsigned short, (__bf16)hi);
    return (unsigned)l | ((unsigned)h << 16);
}
__device__ __forceinline__ float clamp30(float v) {
    return __builtin_fminf(__builtin_fmaxf(v, -30.0f), 30.0f);
}
// h = sigmoid(o)*tanh(sigmoid(i)*tanh(g)); f-gate dead (c_prev=0). Unchanged math.
__device__ __forceinline__ float lstm_h(float ip, float gp, float op) {
    ip = clamp30(ip); gp = clamp30(gp); op = clamp30(op);
    const float Ei = EXP2F(-K1 * ip);
    const float Eg = EXP2F( K2 * gp);
    const float c2 = (Eg - 1.0f) * RCPF((1.0f + Ei) * (Eg + 1.0f));
    const float Eo = EXP2F(-K1 * op);
    const float Ec = EXP2F( K2 * c2);
    return (Ec - 1.0f) * RCPF((1.0f + Eo) * (Ec + 1.0f));
}

// ===========================================================================
// Transposed, barrier-free structure. Per wave (16 batch rows m = lane&15):
//   D1 = Wih0_tile (A) x x^T (B)   -> lane-local activation -> h0^T words
//   D2 = Wih1p_tile (A) x h0^T (B) -> lane-local activation -> h1^T words
//   D3 = Wph_tile  (A) x h1^T (B)  -> policy/value stores
// MFMA layouts (verified by prior passing kernel):
//   A: M-row = lane&15, k = quad*8+j.  B: N-col = lane&15, k = quad*8+j.
//   D: N-col = lane&15, M-row = quad*4+reg.
// h words: hw[w] (w = nc*2+u) = bf16x2 pair h[nc*16 + q*4 + 2u + {0,1}].
// pi-trick: B-frag for k-tile kt := {hw[4kt+j2]}, j2=0..3, i.e. element
// (kt,q,2j2+e) holds h[pi], pi = ((4kt+j2)>>1)*16 + q*4 + ((4kt+j2)&1)*2 + e
// (a bijection on [0,128)). Storing Wih1/Wp with columns permuted by the SAME
// pi at staging time makes sum_k W[pi(k)]*h[pi(k)] = the exact dot product:
// ZERO shuffles / LDS round-trips / barriers between layers.
// Staging granule (row n, slot s; kt=s>>2, qq=s&3) = [W[n][32kt+4qq..+3],
// W[n][32kt+16+4qq..+3]].  Slot XOR-swizzle (s ^ (n&7)) -> 2-way reads (free).
// ===========================================================================
__global__ __launch_bounds__(TPB, 4)
void lstm_fused(const float* __restrict__ x,
                const float* __restrict__ Wih0,
                const float* __restrict__ bih0,
                const float* __restrict__ bhh0,
                const float* __restrict__ Wih1,
                const float* __restrict__ bih1,
                const float* __restrict__ bhh1,
                const float* __restrict__ Wp,
                const float* __restrict__ bp,
                const float* __restrict__ Wv,
                const float* __restrict__ bv,
                float* __restrict__ out)
{
    __shared__ __align__(16) uint4 w0s[384 * 8];   // 48 KB  Wih0 igo, linear k
    __shared__ __align__(16) uint4 w1s[384 * 16];  // 96 KB  Wih1 igo, pi-permuted k
    __shared__ __align__(16) uint4 wph[32 * 16];   //  8 KB  rows 0-15 Wp, 16 Wv, 17-31 zero
    __shared__ float b0s[384];                     // bih0+bhh0, igo-packed
    __shared__ float b1s[384];                     // bih1+bhh1

    const int tid  = threadIdx.x;
    const int wave = tid >> 6;
    const int lane = tid & 63;
    const int q    = lane >> 4;
    const int m    = lane & 15;
    const int row  = blockIdx.x * 256 + wave * 16 + m;   // batch row this lane owns
    const f32x4 vzero = {0.f, 0.f, 0.f, 0.f};

    // ---- x prefetch (HBM, longest latency) issued before weight staging ----
    const float* xp = x + (size_t)row * IN + q * 8;
    F32x8 xr0 = ld8f(xp);        // k = q*8..+7      (kt=0)
    F32x8 xr1 = ld8f(xp + 32);   // k = 32+q*8..+7   (kt=1)
    const float4 bpr = *reinterpret_cast<const float4*>(bp + q * 4);
    const float  bvv = bv[0];

    // ---- Stage Wih0: 3072 granules (row j = g*128+h, 8 slots of 8 cols) ----
#pragma unroll
    for (int r = 0; r < 3; ++r) {
        const int idx = tid + (r << 10);
        const int j = idx >> 3, s = idx & 7;
        const int g = j >> 7, h = j & 127;
        const int srow = h + ((g == 0) ? 0 : (g + 1) * 128);   // i,g,o -> 0,2H,3H
        Frag f = cvt8(ld8f(Wih0 + (size_t)srow * IN + s * 8));
        w0s[(j << 3) + (s ^ (j & 7))] = f.u;
    }
    // ---- Stage Wih1 pi-permuted: 6144 granules (16 slots per row) ----
#pragma unroll
    for (int r = 0; r < 6; ++r) {
        const int idx = tid + (r << 10);
        const int j = idx >> 4, s = idx & 15;
        const int g = j >> 7, h = j & 127;
        const int srow = h + ((g == 0) ? 0 : (g + 1) * 128);
        const int kt = s >> 2, qq = s & 3;
        const float* pA = Wih1 + (size_t)srow * H + kt * 32 + qq * 4;
        Frag f = cvt44(*reinterpret_cast<const float4*>(pA),
                       *reinterpret_cast<const float4*>(pA + 16));
        w1s[(j << 4) + (s ^ (j & 7))] = f.u;
    }
    // ---- Stage heads pi-permuted (+ zero-fill rows 17-31) ----
    if (tid < 512) {
        const int j = tid >> 4, s = tid & 15;
        const int kt = s >> 2, qq = s & 3;
        Frag f;
        if (j <= 16) {
            const float* base = (j < 16) ? (Wp + (size_t)j * H) : Wv;
            const float* pA = base + kt * 32 + qq * 4;
            f = cvt44(*reinterpret_cast<const float4*>(pA),
                      *reinterpret_cast<const float4*>(pA + 16));
        } else {
            f.u = make_uint4(0u, 0u, 0u, 0u);
        }
        wph[(j << 4) + (s ^ (j & 7))] = f.u;
    }
    // ---- Stage biases (igo-packed, bih+bhh pre-summed) ----
    if (tid < 384) {
        const int g = tid >> 7, h = tid & 127;
        const int srow = h + ((g == 0) ? 0 : (g + 1) * 128);
        b0s[tid] = bih0[srow] + bhh0[srow];
    } else if (tid < 768) {
        const int t = tid - 384;
        const int g = t >> 7, h = t & 127;
        const int srow = h + ((g == 0) ? 0 : (g + 1) * 128);
        b1s[t] = bih1[srow] + bhh1[srow];
    }

    __syncthreads();   // the ONLY barrier in the kernel

    const int swz = m & 7;
    Frag xb[2];
    xb[0] = cvt8(xr0);
    xb[1] = cvt8(xr1);

    // ===== Layer 0: D1 = Wih0 x x^T, chunked 16 hidden units at a time =====
    unsigned hw0[16];
#pragma unroll
    for (int nc = 0; nc < 8; ++nc) {
        f32x4 acc[3]; acc[0] = vzero; acc[1] = vzero; acc[2] = vzero;
#pragma unroll
        for (int g = 0; g < 3; ++g) {
            const int n = g * 128 + nc * 16 + m;
#pragma unroll
            for (int kt = 0; kt < 2; ++kt) {
                Frag a; a.u = w0s[(n << 3) + ((kt * 4 + q) ^ swz)];
                acc[g] = __builtin_amdgcn_mfma_f32_16x16x32_bf16(a.v, xb[kt].v, acc[g], 0, 0, 0);
            }
        }
        const f32x4 bI = *reinterpret_cast<const f32x4*>(b0s +       nc * 16 + q * 4);
        const f32x4 bG = *reinterpret_cast<const f32x4*>(b0s + 128 + nc * 16 + q * 4);
        const f32x4 bO = *reinterpret_cast<const f32x4*>(b0s + 256 + nc * 16 + q * 4);
#pragma unroll
        for (int u = 0; u < 2; ++u) {
            const float ha = lstm_h(acc[0][2*u]   + bI[2*u],   acc[1][2*u]   + bG[2*u],   acc[2][2*u]   + bO[2*u]);
            const float hb = lstm_h(acc[0][2*u+1] + bI[2*u+1], acc[1][2*u+1] + bG[2*u+1], acc[2][2*u+1] + bO[2*u+1]);
            hw0[nc * 2 + u] = pk2(ha, hb);
        }
    }

    // ===== Layer 1: D2 = Wih1p x h0^T (B-frags = hw0 words, pi-absorbed) ====
    unsigned hw1[16];
#pragma unroll
    for (int nc = 0; nc < 8; ++nc) {
        f32x4 acc[3]; acc[0] = vzero; acc[1] = vzero; acc[2] = vzero;
#pragma unroll
        for (int kt = 0; kt < 4; ++kt) {
            Frag b; b.u = make_uint4(hw0[4*kt], hw0[4*kt+1], hw0[4*kt+2], hw0[4*kt+3]);
#pragma unroll
            for (int g = 0; g < 3; ++g) {
                const int n = g * 128 + nc * 16 + m;
                Frag a; a.u = w1s[(n << 4) + ((kt * 4 + q) ^ swz)];
                acc[g] = __builtin_amdgcn_mfma_f32_16x16x32_bf16(a.v, b.v, acc[g], 0, 0, 0);
            }
        }
        const f32x4 bI = *reinterpret_cast<const f32x4*>(b1s +       nc * 16 + q * 4);
        const f32x4 bG = *reinterpret_cast<const f32x4*>(b1s + 128 + nc * 16 + q * 4);
        const f32x4 bO = *reinterpret_cast<const f32x4*>(b1s + 256 + nc * 16 + q * 4);
#pragma unroll
        for (int u = 0; u < 2; ++u) {
            const float ha = lstm_h(acc[0][2*u]   + bI[2*u],   acc[1][2*u]   + bG[2*u],   acc[2][2*u]   + bO[2*u]);
            const float hb = lstm_h(acc[0][2*u+1] + bI[2*u+1], acc[1][2*u+1] + bG[2*u+1], acc[2][2*u+1] + bO[2*u+1]);
            hw1[nc * 2 + u] = pk2(ha, hb);
        }
    }

    // ===== Heads: D3 = Wph x h1^T; tile0 rows = policy, tile1 row16 = value =
    f32x4 ap = vzero, av = vzero;
#pragma unroll
    for (int kt = 0; kt < 4; ++kt) {
        Frag b; b.u = make_uint4(hw1[4*kt], hw1[4*kt+1], hw1[4*kt+2], hw1[4*kt+3]);
        Frag a0; a0.u = wph[( m       << 4) + ((kt * 4 + q) ^ swz)];
        ap = __builtin_amdgcn_mfma_f32_16x16x32_bf16(a0.v, b.v, ap, 0, 0, 0);
        Frag a1; a1.u = wph[((16 + m) << 4) + ((kt * 4 + q) ^ swz)];   // (16+m)&7 == m&7
        av = __builtin_amdgcn_mfma_f32_16x16x32_bf16(a1.v, b.v, av, 0, 0, 0);
    }
    // policy: D col = batch m, row = action q*4+r -> one dwordx4 per lane
    f32x4 po;
    po[0] = ap[0] + bpr.x; po[1] = ap[1] + bpr.y;
    po[2] = ap[2] + bpr.z; po[3] = ap[3] + bpr.w;
    *reinterpret_cast<f32x4*>(out + (size_t)row * NA + q * 4) = po;
    // value lives at tile1 in-tile row 0 -> q==0, reg 0
    if (q == 0) out[(size_t)BATCH * NA + row] = av[0] + bvv;
}

extern "C" void kernel_launch(void* const* d_in, const int* in_sizes, int n_in,
                              void* d_out, int out_size, void* d_ws, size_t ws_size,
                              hipStream_t stream) {
    // setup_inputs order: x, Wih0, Whh0, bih0, bhh0, Wih1, Whh1, bih1, bhh1, Wp, bp, Wv, bv
    // Whh0 (idx 2) / Whh1 (idx 6) dead (h_prev = 0); f-gate dead (c_prev = 0).
    lstm_fused<<<dim3(NBLK), dim3(TPB), 0, stream>>>(
        (const float*)d_in[0], (const float*)d_in[1],
        (const float*)d_in[3], (const float*)d_in[4],
        (const float*)d_in[5], (const float*)d_in[7],
        (const float*)d_in[8], (const float*)d_in[9],
        (const float*)d_in[10], (const float*)d_in[11],
        (const float*)d_in[12], (float*)d_out);
}

// Round 2
// 107.251 us; speedup vs baseline: 1.1184x; 1.0005x over previous
//
#include <hip/hip_runtime.h>
#include <hip/hip_bf16.h>

#define BATCH 65536
#define IN    64
#define H     128
#define NA    16
#define NBLK  256      // 1 block per CU, 155 KB LDS
#define TPB   512      // 8 waves; each wave owns 32 batch rows (2 column-sets)

typedef __bf16 bf16x8 __attribute__((ext_vector_type(8)));
typedef float  f32x4  __attribute__((ext_vector_type(4)));

union Frag { uint4 u; bf16x8 v; };
struct F32x8 { float4 a, b; };

#define EXP2F(v) __builtin_amdgcn_exp2f(v)
#define RCPF(v)  __builtin_amdgcn_rcpf(v)
#define K1 1.442695041f   // log2(e)
#define K2 2.885390082f   // 2*log2(e)

__device__ __forceinline__ F32x8 ld8f(const float* p) {
    F32x8 r;
    r.a = *reinterpret_cast<const float4*>(p);
    r.b = *reinterpret_cast<const float4*>(p + 4);
    return r;
}
__device__ __forceinline__ Frag cvt8(F32x8 x) {
    Frag f;
    f.v[0]=(__bf16)x.a.x; f.v[1]=(__bf16)x.a.y; f.v[2]=(__bf16)x.a.z; f.v[3]=(__bf16)x.a.w;
    f.v[4]=(__bf16)x.b.x; f.v[5]=(__bf16)x.b.y; f.v[6]=(__bf16)x.b.z; f.v[7]=(__bf16)x.b.w;
    return f;
}
__device__ __forceinline__ Frag cvt44(float4 a, float4 b) {
    Frag f;
    f.v[0]=(__bf16)a.x; f.v[1]=(__bf16)a.y; f.v[2]=(__bf16)a.z; f.v[3]=(__bf16)a.w;
    f.v[4]=(__bf16)b.x; f.v[5]=(__bf16)b.y; f.v[6]=(__bf16)b.z; f.v[7]=(__bf16)b.w;
    return f;
}
__device__ __forceinline__ unsigned pk2(float lo, float hi) {
    unsigned short l = __builtin_bit_cast(unsigned short, (__bf16)lo);
    unsigned short h = __builtin_bit_cast(unsigned short, (__bf16)hi);
    return (unsigned)l | ((unsigned)h << 16);
}
__device__ __forceinline__ float clamp30(float v) {
    return __builtin_fminf(__builtin_fmaxf(v, -30.0f), 30.0f);
}
// h = sigmoid(o)*tanh(sigmoid(i)*tanh(g)); f-gate dead (c_prev=0).
__device__ __forceinline__ float lstm_h(float ip, float gp, float op) {
    ip = clamp30(ip); gp = clamp30(gp); op = clamp30(op);
    const float Ei = EXP2F(-K1 * ip);
    const float Eg = EXP2F( K2 * gp);
    const float c2 = (Eg - 1.0f) * RCPF((1.0f + Ei) * (Eg + 1.0f));
    const float Eo = EXP2F(-K1 * op);
    const float Ec = EXP2F( K2 * c2);
    return (Ec - 1.0f) * RCPF((1.0f + Eo) * (Ec + 1.0f));
}

// ===========================================================================
// Transposed, barrier-free structure (R1). R2 change: 8 waves x 32 rows/wave
// (two 16-col B-sets) instead of 16 waves x 16 rows. Each weight A-frag
// ds_read_b128 now feeds TWO MFMAs -> LDS read traffic/CU halves
// (2.49 MB -> 1.25 MB), per-wave ILP doubles. Per-SIMD MFMA/VALU/trans
// totals unchanged.
// MFMA layouts: A: M-row=lane&15, k=quad*8+j. B: N-col=lane&15, k=quad*8+j.
//               D: N-col=lane&15, M-row=quad*4+reg.
// pi-trick: next layer's B-frag for k-tile kt := packed h-words {hw[4kt+j2]};
// Wih1/Wp columns stored permuted by the same bijection pi at staging time, so
// no shuffles / LDS round-trips / barriers between layers.
// Staging granule (row n, slot s; kt=s>>2, qq=s&3) = [W[n][32kt+4qq..+3],
// W[n][32kt+16+4qq..+3]].  Slot XOR-swizzle (s ^ (n&7)) -> 2-way reads (free).
// ===========================================================================
__global__ __launch_bounds__(TPB, 2)
void lstm_fused(const float* __restrict__ x,
                const float* __restrict__ Wih0,
                const float* __restrict__ bih0,
                const float* __restrict__ bhh0,
                const float* __restrict__ Wih1,
                const float* __restrict__ bih1,
                const float* __restrict__ bhh1,
                const float* __restrict__ Wp,
                const float* __restrict__ bp,
                const float* __restrict__ Wv,
                const float* __restrict__ bv,
                float* __restrict__ out)
{
    __shared__ __align__(16) uint4 w0s[384 * 8];   // 48 KB  Wih0 igo, linear k
    __shared__ __align__(16) uint4 w1s[384 * 16];  // 96 KB  Wih1 igo, pi-permuted k
    __shared__ __align__(16) uint4 wph[32 * 16];   //  8 KB  rows 0-15 Wp, 16 Wv, 17-31 zero
    __shared__ float b0s[384];                     // bih0+bhh0, igo-packed
    __shared__ float b1s[384];                     // bih1+bhh1

    const int tid  = threadIdx.x;
    const int wave = tid >> 6;
    const int lane = tid & 63;
    const int q    = lane >> 4;
    const int m    = lane & 15;
    const int rbase = blockIdx.x * 256 + wave * 32;      // 32 rows per wave
    const f32x4 vzero = {0.f, 0.f, 0.f, 0.f};

    // ---- x prefetch (HBM, longest latency) issued before weight staging ----
    F32x8 xr[2][2];
#pragma unroll
    for (int s2 = 0; s2 < 2; ++s2) {
        const float* xp = x + (size_t)(rbase + s2 * 16 + m) * IN + q * 8;
        xr[s2][0] = ld8f(xp);
        xr[s2][1] = ld8f(xp + 32);
    }
    const float4 bpr = *reinterpret_cast<const float4*>(bp + q * 4);
    const float  bvv = bv[0];

    // ---- Stage Wih0: 3072 granules (row j = g*128+h, 8 slots of 8 cols) ----
#pragma unroll
    for (int r = 0; r < 6; ++r) {
        const int idx = tid + (r << 9);
        const int j = idx >> 3, s = idx & 7;
        const int g = j >> 7, h = j & 127;
        const int srow = h + ((g == 0) ? 0 : (g + 1) * 128);   // i,g,o -> 0,2H,3H
        Frag f = cvt8(ld8f(Wih0 + (size_t)srow * IN + s * 8));
        w0s[(j << 3) + (s ^ (j & 7))] = f.u;
    }
    // ---- Stage Wih1 pi-permuted: 6144 granules (16 slots per row) ----
#pragma unroll
    for (int r = 0; r < 12; ++r) {
        const int idx = tid + (r << 9);
        const int j = idx >> 4, s = idx & 15;
        const int g = j >> 7, h = j & 127;
        const int srow = h + ((g == 0) ? 0 : (g + 1) * 128);
        const int kt = s >> 2, qq = s & 3;
        const float* pA = Wih1 + (size_t)srow * H + kt * 32 + qq * 4;
        Frag f = cvt44(*reinterpret_cast<const float4*>(pA),
                       *reinterpret_cast<const float4*>(pA + 16));
        w1s[(j << 4) + (s ^ (j & 7))] = f.u;
    }
    // ---- Stage heads pi-permuted (+ zero-fill rows 17-31): 512 granules ----
    {
        const int j = tid >> 4, s = tid & 15;
        const int kt = s >> 2, qq = s & 3;
        Frag f;
        if (j <= 16) {
            const float* base = (j < 16) ? (Wp + (size_t)j * H) : Wv;
            const float* pA = base + kt * 32 + qq * 4;
            f = cvt44(*reinterpret_cast<const float4*>(pA),
                      *reinterpret_cast<const float4*>(pA + 16));
        } else {
            f.u = make_uint4(0u, 0u, 0u, 0u);
        }
        wph[(j << 4) + (s ^ (j & 7))] = f.u;
    }
    // ---- Stage biases (igo-packed, bih+bhh pre-summed) ----
#pragma unroll
    for (int r = 0; r < 2; ++r) {
        const int t = tid + (r << 9);
        if (t < 384) {
            const int g = t >> 7, h = t & 127;
            const int srow = h + ((g == 0) ? 0 : (g + 1) * 128);
            b0s[t] = bih0[srow] + bhh0[srow];
        } else if (t < 768) {
            const int tt = t - 384;
            const int g = tt >> 7, h = tt & 127;
            const int srow = h + ((g == 0) ? 0 : (g + 1) * 128);
            b1s[tt] = bih1[srow] + bhh1[srow];
        }
    }

    __syncthreads();   // the ONLY barrier in the kernel

    const int swz = m & 7;
    Frag xb[2][2];
#pragma unroll
    for (int s2 = 0; s2 < 2; ++s2) {
        xb[s2][0] = cvt8(xr[s2][0]);
        xb[s2][1] = cvt8(xr[s2][1]);
    }

    // ===== Layer 0: D1 = Wih0 x x^T, 16 hidden units x 2 col-sets at a time =
    unsigned hw0[2][16];
#pragma unroll
    for (int nc = 0; nc < 8; ++nc) {
        f32x4 acc[3][2];
#pragma unroll
        for (int g = 0; g < 3; ++g) { acc[g][0] = vzero; acc[g][1] = vzero; }
#pragma unroll
        for (int g = 0; g < 3; ++g) {
            const int n = g * 128 + nc * 16 + m;
#pragma unroll
            for (int kt = 0; kt < 2; ++kt) {
                Frag a; a.u = w0s[(n << 3) + ((kt * 4 + q) ^ swz)];
#pragma unroll
                for (int s2 = 0; s2 < 2; ++s2)
                    acc[g][s2] = __builtin_amdgcn_mfma_f32_16x16x32_bf16(
                        a.v, xb[s2][kt].v, acc[g][s2], 0, 0, 0);
            }
        }
        const f32x4 bI = *reinterpret_cast<const f32x4*>(b0s +       nc * 16 + q * 4);
        const f32x4 bG = *reinterpret_cast<const f32x4*>(b0s + 128 + nc * 16 + q * 4);
        const f32x4 bO = *reinterpret_cast<const f32x4*>(b0s + 256 + nc * 16 + q * 4);
#pragma unroll
        for (int s2 = 0; s2 < 2; ++s2)
#pragma unroll
            for (int u = 0; u < 2; ++u) {
                const float ha = lstm_h(acc[0][s2][2*u]   + bI[2*u],
                                        acc[1][s2][2*u]   + bG[2*u],
                                        acc[2][s2][2*u]   + bO[2*u]);
                const float hb = lstm_h(acc[0][s2][2*u+1] + bI[2*u+1],
                                        acc[1][s2][2*u+1] + bG[2*u+1],
                                        acc[2][s2][2*u+1] + bO[2*u+1]);
                hw0[s2][nc * 2 + u] = pk2(ha, hb);
            }
    }

    // ===== Layer 1: D2 = Wih1p x h0^T (B-frags = hw0 words, pi-absorbed) ====
    unsigned hw1[2][16];
#pragma unroll
    for (int nc = 0; nc < 8; ++nc) {
        f32x4 acc[3][2];
#pragma unroll
        for (int g = 0; g < 3; ++g) { acc[g][0] = vzero; acc[g][1] = vzero; }
#pragma unroll
        for (int kt = 0; kt < 4; ++kt) {
            Frag b[2];
#pragma unroll
            for (int s2 = 0; s2 < 2; ++s2)
                b[s2].u = make_uint4(hw0[s2][4*kt], hw0[s2][4*kt+1],
                                     hw0[s2][4*kt+2], hw0[s2][4*kt+3]);
#pragma unroll
            for (int g = 0; g < 3; ++g) {
                const int n = g * 128 + nc * 16 + m;
                Frag a; a.u = w1s[(n << 4) + ((kt * 4 + q) ^ swz)];
#pragma unroll
                for (int s2 = 0; s2 < 2; ++s2)
                    acc[g][s2] = __builtin_amdgcn_mfma_f32_16x16x32_bf16(
                        a.v, b[s2].v, acc[g][s2], 0, 0, 0);
            }
        }
        const f32x4 bI = *reinterpret_cast<const f32x4*>(b1s +       nc * 16 + q * 4);
        const f32x4 bG = *reinterpret_cast<const f32x4*>(b1s + 128 + nc * 16 + q * 4);
        const f32x4 bO = *reinterpret_cast<const f32x4*>(b1s + 256 + nc * 16 + q * 4);
#pragma unroll
        for (int s2 = 0; s2 < 2; ++s2)
#pragma unroll
            for (int u = 0; u < 2; ++u) {
                const float ha = lstm_h(acc[0][s2][2*u]   + bI[2*u],
                                        acc[1][s2][2*u]   + bG[2*u],
                                        acc[2][s2][2*u]   + bO[2*u]);
                const float hb = lstm_h(acc[0][s2][2*u+1] + bI[2*u+1],
                                        acc[1][s2][2*u+1] + bG[2*u+1],
                                        acc[2][s2][2*u+1] + bO[2*u+1]);
                hw1[s2][nc * 2 + u] = pk2(ha, hb);
            }
    }

    // ===== Heads: D3 = Wph x h1^T; tile0 rows = policy, tile1 row16 = value =
    f32x4 ap[2], av[2];
    ap[0] = vzero; ap[1] = vzero; av[0] = vzero; av[1] = vzero;
#pragma unroll
    for (int kt = 0; kt < 4; ++kt) {
        Frag a0; a0.u = wph[( m       << 4) + ((kt * 4 + q) ^ swz)];
        Frag a1; a1.u = wph[((16 + m) << 4) + ((kt * 4 + q) ^ swz)];   // (16+m)&7 == m&7
#pragma unroll
        for (int s2 = 0; s2 < 2; ++s2) {
            Frag b; b.u = make_uint4(hw1[s2][4*kt], hw1[s2][4*kt+1],
                                     hw1[s2][4*kt+2], hw1[s2][4*kt+3]);
            ap[s2] = __builtin_amdgcn_mfma_f32_16x16x32_bf16(a0.v, b.v, ap[s2], 0, 0, 0);
            av[s2] = __builtin_amdgcn_mfma_f32_16x16x32_bf16(a1.v, b.v, av[s2], 0, 0, 0);
        }
    }
#pragma unroll
    for (int s2 = 0; s2 < 2; ++s2) {
        const int row = rbase + s2 * 16 + m;
        // policy: D col = batch m, row = action q*4+r -> one dwordx4 per lane
        f32x4 po;
        po[0] = ap[s2][0] + bpr.x; po[1] = ap[s2][1] + bpr.y;
        po[2] = ap[s2][2] + bpr.z; po[3] = ap[s2][3] + bpr.w;
        *reinterpret_cast<f32x4*>(out + (size_t)row * NA + q * 4) = po;
        // value lives at tile1 in-tile row 0 -> q==0, reg 0
        if (q == 0) out[(size_t)BATCH * NA + row] = av[s2][0] + bvv;
    }
}

extern "C" void kernel_launch(void* const* d_in, const int* in_sizes, int n_in,
                              void* d_out, int out_size, void* d_ws, size_t ws_size,
                              hipStream_t stream) {
    // setup_inputs order: x, Wih0, Whh0, bih0, bhh0, Wih1, Whh1, bih1, bhh1, Wp, bp, Wv, bv
    // Whh0 (idx 2) / Whh1 (idx 6) dead (h_prev = 0); f-gate dead (c_prev = 0).
    lstm_fused<<<dim3(NBLK), dim3(TPB), 0, stream>>>(
        (const float*)d_in[0], (const float*)d_in[1],
        (const float*)d_in[3], (const float*)d_in[4],
        (const float*)d_in[5], (const float*)d_in[7],
        (const float*)d_in[8], (const float*)d_in[9],
        (const float*)d_in[10], (const float*)d_in[11],
        (const float*)d_in[12], (float*)d_out);
}